// Round 6
// baseline (353.367 us; speedup 1.0000x reference)
//
#include <hip/hip_runtime.h>
#include <math.h>

// Problem constants (match reference)
#define BB 8
#define CC 64
#define HH 256
#define WW 256
constexpr int TILE_H = 32;            // output tile rows
constexpr int TILE_W = 64;            // output tile cols
constexpr int RAD    = 9;             // diagonal strip radius
constexpr int HALO   = RAD + 1;       // + conv radius 1 = 10
constexpr int NR     = TILE_H + 2 * HALO;   // 52 input rows
constexpr int NC     = 88;                  // input cols: [tw-12, tw+76), float4-aligned
constexpr int COL0   = 12;            // halo cols before tile origin (4-aligned)
constexpr int SNR    = TILE_H + 2;    // 34 stripsum rows
constexpr int SNC    = TILE_W + 2;    // 66 stripsum cols
constexpr int SS     = 68;            // stripsum LDS stride
constexpr float INV_TAPS = 1.0f / 19.0f;
constexpr float BN_EPS = 1e-5f;

// Module-owned device globals for cross-kernel stats.
__device__ double g_stats[2 * CC];   // sum, sumsq per channel

// PASS 0: y = dwconv3x3(stripsum(x)); accumulate per-channel sum/sumsq.
// PASS 1: recompute y; derive scale/shift from g_stats; out = gelu(y*scale+shift).
//
// KEY semantics fix (round-5 post-mortem): the reference conv zero-pads XS
// (the stripsum output), NOT x. S entries whose xs-coordinate lies outside
// the image must be ZERO, not the stripsum of zero-padded x.
template <int PASS>
__global__ __launch_bounds__(256) void fused_kernel(
    const float* __restrict__ x,
    const float* __restrict__ wk,     // [C, 9]
    const float* __restrict__ gamma,
    const float* __restrict__ beta,
    float* __restrict__ out)
{
    __shared__ float IN[NR][NC];      // 52 x 88 x 4B = 18304 B
    __shared__ float S[SNR][SS];      // 34 x 68 x 4B =  9248 B
    __shared__ float red[8];

    const int bid  = blockIdx.x;
    const int tcol = bid & 3;                 // 4 tiles across (64 wide)
    const int trow = (bid >> 2) & 7;          // 8 tiles down (32 tall)
    const int ch   = (bid >> 5) & 63;
    const int b    = bid >> 11;
    const int th   = trow * TILE_H;
    const int tw   = tcol * TILE_W;
    const int tid  = threadIdx.x;

    const float* __restrict__ xp = x + (size_t)(b * CC + ch) * (HH * WW);

    // per-channel conv weights, pre-scaled by 1/19 (ch uniform -> scalar loads)
    float wgt[9];
#pragma unroll
    for (int k = 0; k < 9; ++k) wgt[k] = wk[ch * 9 + k] * INV_TAPS;

    // ---- Stage 1: global -> LDS, all-float4, zero fill at image edges ----
    // rows th-10 .. th+41 ; cols tw-12 .. tw+75 (every float4 fully in or out)
    for (int idx = tid; idx < NR * (NC / 4); idx += 256) {
        int r  = idx / (NC / 4);
        int c4 = idx - r * (NC / 4);
        int gh = th - HALO + r;
        int gw = tw - COL0 + (c4 << 2);
        float4 v = make_float4(0.f, 0.f, 0.f, 0.f);
        if ((unsigned)gh < HH && (unsigned)gw < WW)
            v = *(const float4*)&xp[gh * WW + gw];
        *(float4*)&IN[r][c4 << 2] = v;
    }
    __syncthreads();

    // ---- Stage 2: 19-tap diagonal strip sum, diagonal sliding segments ----
    // S[si][sj] = stripsum at xs[th+si-1][tw+sj-1]; ZERO if outside image
    // (conv's zero padding applies to xs, not x).
    for (int seg = tid; seg < 9 * 69; seg += 256) {
        int bi  = seg / 69;
        int sj0 = (seg - bi * 69) - 3;
        int si0 = bi * 4;
        int t0  = sj0 < 0 ? -sj0 : 0;
        int tmax = SNR - si0; if (tmax > 4) tmax = 4;
        if (SNC - sj0 < tmax) tmax = SNC - sj0;
        if (t0 < tmax) {
            int si = si0 + t0, sj = sj0 + t0;
            int gr = th + si - 1, gc = tw + sj - 1;   // xs coords
            float run = 0.f;
#pragma unroll
            for (int k = 0; k < 19; ++k) run += IN[si + k][sj + 2 + k];
            S[si][sj] = ((unsigned)gr < HH && (unsigned)gc < WW) ? run : 0.f;
            for (int t = t0 + 1; t < tmax; ++t) {
                ++si; ++sj; ++gr; ++gc;
                run += IN[si + 18][sj + 2 + 18] - IN[si - 1][sj + 2 - 1];
                S[si][sj] = ((unsigned)gr < HH && (unsigned)gc < WW) ? run : 0.f;
            }
        }
    }
    __syncthreads();

    // ---- Stage 3: depthwise 3x3 (weights pre-scaled by 1/19) ----
    // thread -> (row i0 + {0,16}, col group j4); 16 lanes per row = 256B stores
    const int i0 = tid >> 4;            // 0..15
    const int j4 = (tid & 15) << 2;     // 0,4,..,60

    float s1 = 0.f, s2 = 0.f;           // PASS 0 accumulators
    float scale = 0.f, shift = 0.f;
    if (PASS == 1) {
        // derive BN affine from accumulated stats (uniform per block)
        const double N = (double)BB * HH * WW;
        double mean = g_stats[ch] / N;
        double var  = g_stats[CC + ch] / N - mean * mean;
        scale = gamma[ch] * (float)(1.0 / sqrt(var + (double)BN_EPS));
        shift = beta[ch] - (float)mean * scale;
    }

#pragma unroll
    for (int half = 0; half < 2; ++half) {
        const int i = i0 + half * 16;
        float4 a0 = *(const float4*)&S[i][j4];
        float2 b0 = *(const float2*)&S[i][j4 + 4];
        float4 a1 = *(const float4*)&S[i + 1][j4];
        float2 b1 = *(const float2*)&S[i + 1][j4 + 4];
        float4 a2 = *(const float4*)&S[i + 2][j4];
        float2 b2 = *(const float2*)&S[i + 2][j4 + 4];
        float r0[6] = {a0.x, a0.y, a0.z, a0.w, b0.x, b0.y};
        float r1[6] = {a1.x, a1.y, a1.z, a1.w, b1.x, b1.y};
        float r2[6] = {a2.x, a2.y, a2.z, a2.w, b2.x, b2.y};
        float y[4];
#pragma unroll
        for (int q = 0; q < 4; ++q) {
            y[q] = wgt[0] * r0[q] + wgt[1] * r0[q + 1] + wgt[2] * r0[q + 2]
                 + wgt[3] * r1[q] + wgt[4] * r1[q + 1] + wgt[5] * r1[q + 2]
                 + wgt[6] * r2[q] + wgt[7] * r2[q + 1] + wgt[8] * r2[q + 2];
        }
        if (PASS == 0) {
#pragma unroll
            for (int q = 0; q < 4; ++q) { s1 += y[q]; s2 += y[q] * y[q]; }
        } else {
            float4 o;
#pragma unroll
            for (int q = 0; q < 4; ++q) {
                float v = y[q] * scale + shift;
                ((float*)&o)[q] = 0.5f * v * (1.0f + erff(v * 0.70710678118654752f));
            }
            float* __restrict__ po =
                out + ((size_t)(b * CC + ch) * HH + (th + i)) * WW + tw + j4;
            *(float4*)po = o;
        }
    }

    if (PASS == 0) {
        // wave (64-lane) reduce, then cross-wave via LDS, one atomic pair/block
#pragma unroll
        for (int off = 32; off > 0; off >>= 1) {
            s1 += __shfl_down(s1, off);
            s2 += __shfl_down(s2, off);
        }
        if ((tid & 63) == 0) { red[(tid >> 6) * 2] = s1; red[(tid >> 6) * 2 + 1] = s2; }
        __syncthreads();
        if (tid == 0) {
            float t1 = red[0] + red[2] + red[4] + red[6];
            float t2 = red[1] + red[3] + red[5] + red[7];
            atomicAdd(&g_stats[ch], (double)t1);
            atomicAdd(&g_stats[CC + ch], (double)t2);
        }
    }
}

__global__ void zero_stats_kernel() {
    int t = threadIdx.x;
    if (t < 2 * CC) g_stats[t] = 0.0;
}

extern "C" void kernel_launch(void* const* d_in, const int* in_sizes, int n_in,
                              void* d_out, int out_size, void* d_ws, size_t ws_size,
                              hipStream_t stream) {
    const float* x     = (const float*)d_in[0];
    const float* wk    = (const float*)d_in[1];
    const float* gamma = (const float*)d_in[2];
    const float* beta  = (const float*)d_in[3];
    float* out = (float*)d_out;

    const int nblocks = BB * CC * (HH / TILE_H) * (WW / TILE_W);     // 16384

    zero_stats_kernel<<<1, 128, 0, stream>>>();
    fused_kernel<0><<<nblocks, 256, 0, stream>>>(x, wk, gamma, beta, nullptr);
    fused_kernel<1><<<nblocks, 256, 0, stream>>>(x, wk, gamma, beta, out);
}

// Round 9
// 328.286 us; speedup vs baseline: 1.0764x; 1.0764x over previous
//
#include <hip/hip_runtime.h>
#include <math.h>

// Problem constants (match reference)
#define BB 8
#define CC 64
#define HH 256
#define WW 256
constexpr int TILE_H = 32;            // output tile rows
constexpr int TILE_W = 64;            // output tile cols
constexpr int RAD    = 9;             // diagonal strip radius
constexpr int HALO   = RAD + 1;       // + conv radius 1 = 10
constexpr int NR     = TILE_H + 2 * HALO;   // 52 input rows
constexpr int NC     = 88;                  // input cols: [tw-12, tw+76), float4-aligned
constexpr int COL0   = 12;            // halo cols before tile origin (4-aligned)
constexpr int SNR    = TILE_H + 2;    // 34 stripsum rows
constexpr int SNC    = TILE_W + 2;    // 66 stripsum cols
constexpr int SS     = 68;            // stripsum LDS stride
constexpr float INV_TAPS = 1.0f / 19.0f;
constexpr float BN_EPS = 1e-5f;
constexpr size_t Y_BYTES = (size_t)BB * CC * HH * WW * sizeof(float); // 128 MiB

// Module-owned device globals for cross-kernel stats.
__device__ double g_stats[2 * CC];   // sum, sumsq per channel

// PASS 0: y = dwconv3x3(stripsum(x)); accumulate per-channel sum/sumsq.
//         If STORE_Y, also write y to workspace (so pass B is pure streaming).
// PASS 1: recompute y; derive scale/shift from g_stats; out = gelu(y*scale+shift).
//         (fallback path when workspace is too small)
// Reference semantics: the 3x3 conv zero-pads XS (stripsum output), NOT x.
template <int PASS, bool STORE_Y>
__global__ __launch_bounds__(256) void fused_kernel(
    const float* __restrict__ x,
    const float* __restrict__ wk,     // [C, 9]
    const float* __restrict__ gamma,
    const float* __restrict__ beta,
    float* __restrict__ out)          // y workspace (PASS 0+STORE_Y) or final out (PASS 1)
{
    __shared__ float IN[NR][NC];      // 52 x 88 x 4B = 18304 B
    __shared__ float S[SNR][SS];      // 34 x 68 x 4B =  9248 B
    __shared__ float red[8];

    const int bid  = blockIdx.x;
    const int tcol = bid & 3;                 // 4 tiles across (64 wide)
    const int trow = (bid >> 2) & 7;          // 8 tiles down (32 tall)
    const int ch   = (bid >> 5) & 63;
    const int b    = bid >> 11;
    const int th   = trow * TILE_H;
    const int tw   = tcol * TILE_W;
    const int tid  = threadIdx.x;

    const float* __restrict__ xp = x + (size_t)(b * CC + ch) * (HH * WW);

    // per-channel conv weights, pre-scaled by 1/19 (ch uniform -> scalar loads)
    float wgt[9];
#pragma unroll
    for (int k = 0; k < 9; ++k) wgt[k] = wk[ch * 9 + k] * INV_TAPS;

    // ---- Stage 1: global -> LDS, all-float4, zero fill at image edges ----
    for (int idx = tid; idx < NR * (NC / 4); idx += 256) {
        int r  = idx / (NC / 4);
        int c4 = idx - r * (NC / 4);
        int gh = th - HALO + r;
        int gw = tw - COL0 + (c4 << 2);
        float4 v = make_float4(0.f, 0.f, 0.f, 0.f);
        if ((unsigned)gh < HH && (unsigned)gw < WW)
            v = *(const float4*)&xp[gh * WW + gw];
        *(float4*)&IN[r][c4 << 2] = v;
    }
    __syncthreads();

    // ---- Stage 2: 19-tap diagonal strip sum, diagonal sliding segments ----
    // S[si][sj] = stripsum at xs[th+si-1][tw+sj-1]; ZERO if outside image.
    for (int seg = tid; seg < 9 * 69; seg += 256) {
        int bi  = seg / 69;
        int sj0 = (seg - bi * 69) - 3;
        int si0 = bi * 4;
        int t0  = sj0 < 0 ? -sj0 : 0;
        int tmax = SNR - si0; if (tmax > 4) tmax = 4;
        if (SNC - sj0 < tmax) tmax = SNC - sj0;
        if (t0 < tmax) {
            int si = si0 + t0, sj = sj0 + t0;
            int gr = th + si - 1, gc = tw + sj - 1;   // xs coords
            float run = 0.f;
#pragma unroll
            for (int k = 0; k < 19; ++k) run += IN[si + k][sj + 2 + k];
            S[si][sj] = ((unsigned)gr < HH && (unsigned)gc < WW) ? run : 0.f;
            for (int t = t0 + 1; t < tmax; ++t) {
                ++si; ++sj; ++gr; ++gc;
                run += IN[si + 18][sj + 2 + 18] - IN[si - 1][sj + 2 - 1];
                S[si][sj] = ((unsigned)gr < HH && (unsigned)gc < WW) ? run : 0.f;
            }
        }
    }
    __syncthreads();

    // ---- Stage 3: depthwise 3x3 (weights pre-scaled by 1/19) ----
    const int i0 = tid >> 4;            // 0..15
    const int j4 = (tid & 15) << 2;     // 0,4,..,60

    float s1 = 0.f, s2 = 0.f;           // PASS 0 accumulators
    float scale = 0.f, shift = 0.f;
    if (PASS == 1) {
        const double N = (double)BB * HH * WW;
        double mean = g_stats[ch] / N;
        double var  = g_stats[CC + ch] / N - mean * mean;
        scale = gamma[ch] * (float)(1.0 / sqrt(var + (double)BN_EPS));
        shift = beta[ch] - (float)mean * scale;
    }

#pragma unroll
    for (int half = 0; half < 2; ++half) {
        const int i = i0 + half * 16;
        float4 a0 = *(const float4*)&S[i][j4];
        float2 b0 = *(const float2*)&S[i][j4 + 4];
        float4 a1 = *(const float4*)&S[i + 1][j4];
        float2 b1 = *(const float2*)&S[i + 1][j4 + 4];
        float4 a2 = *(const float4*)&S[i + 2][j4];
        float2 b2 = *(const float2*)&S[i + 2][j4 + 4];
        float r0[6] = {a0.x, a0.y, a0.z, a0.w, b0.x, b0.y};
        float r1[6] = {a1.x, a1.y, a1.z, a1.w, b1.x, b1.y};
        float r2[6] = {a2.x, a2.y, a2.z, a2.w, b2.x, b2.y};
        float y[4];
#pragma unroll
        for (int q = 0; q < 4; ++q) {
            y[q] = wgt[0] * r0[q] + wgt[1] * r0[q + 1] + wgt[2] * r0[q + 2]
                 + wgt[3] * r1[q] + wgt[4] * r1[q + 1] + wgt[5] * r1[q + 2]
                 + wgt[6] * r2[q] + wgt[7] * r2[q + 1] + wgt[8] * r2[q + 2];
        }
        if (PASS == 0) {
#pragma unroll
            for (int q = 0; q < 4; ++q) { s1 += y[q]; s2 += y[q] * y[q]; }
            if (STORE_Y) {
                float* __restrict__ po =
                    out + ((size_t)(b * CC + ch) * HH + (th + i)) * WW + tw + j4;
                *(float4*)po = make_float4(y[0], y[1], y[2], y[3]);
            }
        } else {
            float4 o;
#pragma unroll
            for (int q = 0; q < 4; ++q) {
                float v = y[q] * scale + shift;
                ((float*)&o)[q] = 0.5f * v * (1.0f + erff(v * 0.70710678118654752f));
            }
            float* __restrict__ po =
                out + ((size_t)(b * CC + ch) * HH + (th + i)) * WW + tw + j4;
            *(float4*)po = o;
        }
    }

    if (PASS == 0) {
#pragma unroll
        for (int off = 32; off > 0; off >>= 1) {
            s1 += __shfl_down(s1, off);
            s2 += __shfl_down(s2, off);
        }
        if ((tid & 63) == 0) { red[(tid >> 6) * 2] = s1; red[(tid >> 6) * 2 + 1] = s2; }
        __syncthreads();
        if (tid == 0) {
            float t1 = red[0] + red[2] + red[4] + red[6];
            float t2 = red[1] + red[3] + red[5] + red[7];
            atomicAdd(&g_stats[ch], (double)t1);
            atomicAdd(&g_stats[CC + ch], (double)t2);
        }
    }
}

// Pass B (stored-y path): pure streaming BN + exact GELU.
// 2048 blocks; each handles a quarter of one (b,ch) plane (16384 floats).
__global__ __launch_bounds__(256) void bn_gelu_kernel(
    const float* __restrict__ y,
    const float* __restrict__ gamma,
    const float* __restrict__ beta,
    float* __restrict__ out)
{
    const int plane = blockIdx.x >> 2;        // 0..511  (b*CC + ch)
    const int part  = blockIdx.x & 3;
    const int ch    = plane & 63;

    const double N = (double)BB * HH * WW;
    double mean = g_stats[ch] / N;
    double var  = g_stats[CC + ch] / N - mean * mean;
    const float scale = gamma[ch] * (float)(1.0 / sqrt(var + (double)BN_EPS));
    const float shift = beta[ch] - (float)mean * scale;

    const size_t base = (size_t)plane * (HH * WW) + (size_t)part * (HH * WW / 4);
    const float4* __restrict__ yp = (const float4*)(y + base);
    float4* __restrict__ op = (float4*)(out + base);

#pragma unroll
    for (int it = 0; it < 16; ++it) {
        int i = threadIdx.x + it * 256;       // 4096 float4 per part
        float4 v = yp[i];
        float4 o;
#pragma unroll
        for (int q = 0; q < 4; ++q) {
            float t = ((const float*)&v)[q] * scale + shift;
            ((float*)&o)[q] = 0.5f * t * (1.0f + erff(t * 0.70710678118654752f));
        }
        op[i] = o;
    }
}

__global__ void zero_stats_kernel() {
    int t = threadIdx.x;
    if (t < 2 * CC) g_stats[t] = 0.0;
}

extern "C" void kernel_launch(void* const* d_in, const int* in_sizes, int n_in,
                              void* d_out, int out_size, void* d_ws, size_t ws_size,
                              hipStream_t stream) {
    const float* x     = (const float*)d_in[0];
    const float* wk    = (const float*)d_in[1];
    const float* gamma = (const float*)d_in[2];
    const float* beta  = (const float*)d_in[3];
    float* out = (float*)d_out;

    const int nblocks = BB * CC * (HH / TILE_H) * (WW / TILE_W);     // 16384

    zero_stats_kernel<<<1, 128, 0, stream>>>();
    if (ws_size >= Y_BYTES) {
        // compute y once; stream BN+GELU from stored y
        float* yw = (float*)d_ws;
        fused_kernel<0, true><<<nblocks, 256, 0, stream>>>(x, wk, gamma, beta, yw);
        bn_gelu_kernel<<<BB * CC * 4, 256, 0, stream>>>(yw, gamma, beta, out);
    } else {
        // fallback: recompute y in pass 1 (verified round-6 path)
        fused_kernel<0, false><<<nblocks, 256, 0, stream>>>(x, wk, gamma, beta, nullptr);
        fused_kernel<1, false><<<nblocks, 256, 0, stream>>>(x, wk, gamma, beta, out);
    }
}